// Round 6
// baseline (258.427 us; speedup 1.0000x reference)
//
#include <hip/hip_runtime.h>
#include <stdint.h>

#define DIM 1024
#define SEQ 2048
#define BATCH 4
#define ROWS (BATCH*SEQ)          /* 8192 */
// attention scale folded into Q: 0.125 * log2(e)
#define QSCALE 0.1803368801111f

typedef __attribute__((ext_vector_type(8))) short bf16x8;   // 8 bf16 in 4 VGPRs
typedef __attribute__((ext_vector_type(4))) float f32x4;
typedef __attribute__((ext_vector_type(8))) _Float16 f16x8;
typedef __attribute__((ext_vector_type(2))) __fp16 fp16x2_raw;  // cvt_pkrtz return type

#if __has_builtin(__builtin_amdgcn_exp2f)
#define EXP2F(x) __builtin_amdgcn_exp2f(x)
#else
#define EXP2F(x) __expf((x) * 0.69314718056f)
#endif

#define MFMA_BF16_K32(a,b,c) __builtin_amdgcn_mfma_f32_16x16x32_bf16(a,b,c,0,0,0)
#define MFMA_F16_K32(a,b,c)  __builtin_amdgcn_mfma_f32_16x16x32_f16(a,b,c,0,0,0)

// ---- fp32 -> bf16 RNE ----
__device__ __forceinline__ unsigned short f2bf(float f) {
  union { float f; unsigned int u; } v; v.f = f;
  unsigned int u = v.u;
  return (unsigned short)((u + 0x7FFFu + ((u >> 16) & 1u)) >> 16);
}

// ---- fp32 -> fp16 RNE (bits) ----
__device__ __forceinline__ unsigned short f2h(float f) {
  union { _Float16 h; unsigned short u; } v;
  v.h = (_Float16)f;
  return v.u;
}

// pack two f32 -> fp16x2 dword (v_cvt_pkrtz_f16_f32), returned as raw bits
__device__ __forceinline__ unsigned int pkrtz_bits(float lo, float hi) {
  union { fp16x2_raw h; unsigned int u; } v;
  v.h = __builtin_amdgcn_cvt_pkrtz(lo, hi);
  return v.u;
}

// ---- async global->LDS, 16B per lane (wave-uniform LDS base + lane*16) ----
__device__ __forceinline__ void gload_lds16(const void* g, void* l) {
  __builtin_amdgcn_global_load_lds(
      (const __attribute__((address_space(1))) unsigned int*)g,
      (__attribute__((address_space(3))) unsigned int*)l,
      16, 0, 0);
}

// ---- fused cast kernel: x (8M) | w_qkv (3M) | w_proj (1M) fp32 -> bf16 ----
__global__ void cast_all(const float* __restrict__ x,
                         const float* __restrict__ wq,
                         const float* __restrict__ wp,
                         unsigned short* __restrict__ xb,
                         unsigned short* __restrict__ wqb,
                         unsigned short* __restrict__ wpb) {
  const int i = (blockIdx.x * blockDim.x + threadIdx.x) * 4;
  const float* src;
  unsigned short* dst;
  int off;
  if (i < ROWS * DIM)                 { src = x;  dst = xb;  off = i; }
  else if (i < ROWS * DIM + 3 * DIM * DIM) { src = wq; dst = wqb; off = i - ROWS * DIM; }
  else                                { src = wp; dst = wpb; off = i - ROWS * DIM - 3 * DIM * DIM; }
  float4 f = *(const float4*)(src + off);
  ushort4 o;
  o.x = f2bf(f.x); o.y = f2bf(f.y); o.z = f2bf(f.z); o.w = f2bf(f.w);
  *(ushort4*)(dst + off) = o;
}

// swapped/normal MFMA helper (SWAP transposes the C fragment)
template<int SWAP>
__device__ __forceinline__ f32x4 mm(bf16x8 a, bf16x8 b, f32x4 c) {
  if constexpr (SWAP) return __builtin_amdgcn_mfma_f32_16x16x32_bf16(b, a, c, 0, 0, 0);
  else                return __builtin_amdgcn_mfma_f32_16x16x32_bf16(a, b, c, 0, 0, 0);
}

// ---- 8-phase 256x256 Q/K GEMM (T2+T3+T4+T5 template, plain HIP) ----
// C[8192, n0..n0+256) = X @ Wqkv^T over K=1024 (16 K-tiles of 64).
// SWAP=1: Q/K columns (n0 in [0,2048)), transposed C frags -> vectorized
//         [bh][n][d] ushort4 writes (Q scaled by QSCALE).
// Per K-tile t: 4 phases x {ds-subtile | 1-2 stage | bar lgkm mfma(16) bar},
// vmcnt(6) once per tile (never 0 in main loop). LDS rows 128B -> XOR
// swizzle chunk^=(row&7), applied as pre-swizzled GLOBAL source + swizzled
// ds_read address (gload_lds writes linearly).
// 256 blocks = exactly one full round at 1 block/CU (128KB LDS).
template<int SWAP, int NTX>
__global__ __launch_bounds__(512, 2) void gemm_qkv8(
    const unsigned short* __restrict__ A,    // [8192][1024] bf16
    const unsigned short* __restrict__ W,    // [3072][1024] bf16
    unsigned short* __restrict__ qb,
    unsigned short* __restrict__ kb,
    unsigned short* __restrict__ vtb) {
  constexpr int K = DIM;
  constexpr int NT = K / 64;                 // 16 K-tiles
  constexpr int N0B = SWAP ? 0 : 2048;
  __shared__ unsigned short Al[2][256 * 64]; // 64KB
  __shared__ unsigned short Bl[2][256 * 64]; // 64KB

  const int tid  = threadIdx.x;
  const int wave = tid >> 6, lane = tid & 63;
  const int quad = lane >> 4, l16 = lane & 15;
  const int wm = wave >> 2, wn = wave & 3;   // 2 x 4 wave grid

  // XCD-bijective block swizzle (nwg % 8 == 0)
  constexpr int nwg = NTX * 32;
  int id = blockIdx.y * NTX + blockIdx.x;
  id = (id & 7) * (nwg >> 3) + (id >> 3);
  const int bx = id % NTX, by = id / NTX;
  const int m0 = by * 256, n0 = N0B + bx * 256;

  // staging addresses: lane -> (row = wave*8 + lane>>3, src chunk pre-swizzled)
  const int srow8 = lane >> 3;               // 0..7, == (lds row & 7)
  const int schk  = (lane & 7) ^ srow8;      // involution: lds chunk ^ row&7
  const unsigned short* Ast = A + (size_t)(m0 + wave * 8 + srow8) * K + (schk << 3);
  const unsigned short* Bst = W + (size_t)(n0 + wave * 8 + srow8) * K + (schk << 3);

  // one block-wide 64-row slab load: 1 gload_lds per wave (8 rows/wave)
  auto stg = [&](const unsigned short* g, int R0, int kt, unsigned short* l) {
    gload_lds16((const void*)(g + (size_t)R0 * K + kt),
                (void*)(l + (R0 + wave * 8) * 64));
  };
  // swizzled fragment read: row rb+idx*16+l16, k-chunk kk*4+quad
  auto ldf = [&](const unsigned short* base, int rb, int idx, int kk) -> bf16x8 {
    const int r = rb + idx * 16 + l16;
    return *(const bf16x8*)&base[r * 64 + (((kk * 4 + quad) ^ (l16 & 7)) << 3)];
  };

  f32x4 acc[8][4];
#pragma unroll
  for (int i = 0; i < 8; ++i)
#pragma unroll
    for (int j = 0; j < 4; ++j) acc[i][j] = (f32x4)0.f;

  // prologue: tile 0 complete (8 loads, oldest), tile 1 all but B-h1 (6)
  stg(Ast, 0, 0, Al[0]);  stg(Ast, 128, 0, Al[0]);
  stg(Ast, 64, 0, Al[0]); stg(Ast, 192, 0, Al[0]);
  stg(Bst, 0, 0, Bl[0]);  stg(Bst, 64, 0, Bl[0]);
  stg(Bst, 128, 0, Bl[0]); stg(Bst, 192, 0, Bl[0]);
  stg(Ast, 0, 64, Al[1]);  stg(Ast, 128, 64, Al[1]);
  stg(Bst, 0, 64, Bl[1]);  stg(Bst, 64, 64, Bl[1]);
  stg(Ast, 64, 64, Al[1]); stg(Ast, 192, 64, Al[1]);
  asm volatile("s_waitcnt vmcnt(6)" ::: "memory");  // tile 0 landed
  __builtin_amdgcn_s_barrier();

  bf16x8 af[4][2], bf[4][2];
  int buf = 0;
  for (int t = 0; t < NT; ++t, buf ^= 1) {
    const unsigned short* Ac = Al[buf];
    const unsigned short* Bc = Bl[buf];
    unsigned short* Asg = Al[buf];   // tile t+2 reuses current buffer
    unsigned short* Bsg = Bl[buf];
    const int kt2 = (t + 2) * 64;

    // ---------- P1 ----------
#pragma unroll
    for (int mi = 0; mi < 4; ++mi) {
      af[mi][0] = ldf(Ac, wm * 128, mi, 0);
      af[mi][1] = ldf(Ac, wm * 128, mi, 1);
    }
#pragma unroll
    for (int ni = 0; ni < 2; ++ni) {
      bf[ni][0] = ldf(Bc, wn * 64, ni, 0);
      bf[ni][1] = ldf(Bc, wn * 64, ni, 1);
    }
    if (t + 1 < NT) {  // B-h1 of tile t+1 (region free since tile t-1)
      stg(Bst, 128, (t + 1) * 64, Bl[buf ^ 1]);
      stg(Bst, 192, (t + 1) * 64, Bl[buf ^ 1]);
    }
    __builtin_amdgcn_s_barrier();
    asm volatile("s_waitcnt lgkmcnt(0)" ::: "memory");
    __builtin_amdgcn_s_setprio(1);
#pragma unroll
    for (int mi = 0; mi < 4; ++mi)
#pragma unroll
      for (int ni = 0; ni < 2; ++ni)
#pragma unroll
        for (int kk = 0; kk < 2; ++kk)
          acc[mi][ni] = mm<SWAP>(af[mi][kk], bf[ni][kk], acc[mi][ni]);
    __builtin_amdgcn_s_setprio(0);
    __builtin_amdgcn_s_barrier();

    // ---------- P2 ----------
#pragma unroll
    for (int ni = 2; ni < 4; ++ni) {
      bf[ni][0] = ldf(Bc, wn * 64, ni, 0);
      bf[ni][1] = ldf(Bc, wn * 64, ni, 1);
    }
    if (t + 2 < NT) {  // A rows {0-63,128-191}: freed by P1
      stg(Ast, 0, kt2, Asg);
      stg(Ast, 128, kt2, Asg);
    }
    __builtin_amdgcn_s_barrier();
    asm volatile("s_waitcnt lgkmcnt(0)" ::: "memory");
    __builtin_amdgcn_s_setprio(1);
#pragma unroll
    for (int mi = 0; mi < 4; ++mi)
#pragma unroll
      for (int ni = 2; ni < 4; ++ni)
#pragma unroll
        for (int kk = 0; kk < 2; ++kk)
          acc[mi][ni] = mm<SWAP>(af[mi][kk], bf[ni][kk], acc[mi][ni]);
    __builtin_amdgcn_s_setprio(0);
    __builtin_amdgcn_s_barrier();

    // ---------- P3 ----------
#pragma unroll
    for (int mi = 0; mi < 4; ++mi) {
      af[mi][0] = ldf(Ac, wm * 128, mi + 4, 0);
      af[mi][1] = ldf(Ac, wm * 128, mi + 4, 1);
    }
    if (t + 2 < NT) {  // B rows {0-127}: all B freed by P2
      stg(Bst, 0, kt2, Bsg);
      stg(Bst, 64, kt2, Bsg);
    }
    __builtin_amdgcn_s_barrier();
    asm volatile("s_waitcnt lgkmcnt(0)" ::: "memory");
    __builtin_amdgcn_s_setprio(1);
#pragma unroll
    for (int mi = 0; mi < 4; ++mi)
#pragma unroll
      for (int ni = 2; ni < 4; ++ni)
#pragma unroll
        for (int kk = 0; kk < 2; ++kk)
          acc[mi + 4][ni] = mm<SWAP>(af[mi][kk], bf[ni][kk], acc[mi + 4][ni]);
    __builtin_amdgcn_s_setprio(0);
    __builtin_amdgcn_s_barrier();

    // ---------- P4 ----------
    if (t + 2 < NT) {  // A rows {64-127,192-255}: freed by P3
      stg(Ast, 64, kt2, Asg);
      stg(Ast, 192, kt2, Asg);
      asm volatile("s_waitcnt vmcnt(6)" ::: "memory");  // tile t+1 landed
    } else {
      asm volatile("s_waitcnt vmcnt(0)" ::: "memory");
    }
    __builtin_amdgcn_s_barrier();
    __builtin_amdgcn_s_setprio(1);
#pragma unroll
    for (int mi = 0; mi < 4; ++mi)
#pragma unroll
      for (int ni = 0; ni < 2; ++ni)
#pragma unroll
        for (int kk = 0; kk < 2; ++kk)
          acc[mi + 4][ni] = mm<SWAP>(af[mi][kk], bf[ni][kk], acc[mi + 4][ni]);
    __builtin_amdgcn_s_setprio(0);
    __builtin_amdgcn_s_barrier();
  }

  // ---------- epilogue ----------
  if constexpr (SWAP) {
    // transposed frags: lane col=l16 -> token, row=quad*4+r -> feature
    const float sc = (n0 < 1024) ? QSCALE : 1.f;
    unsigned short* base = (n0 < 1024) ? qb : kb;
#pragma unroll
    for (int mi = 0; mi < 8; ++mi) {
      const int tok = m0 + wm * 128 + mi * 16 + l16;
      const int b = tok >> 11, n = tok & 2047;
#pragma unroll
      for (int ni = 0; ni < 4; ++ni) {
        const int f0 = n0 + wn * 64 + ni * 16 + quad * 4;
        const int h = (f0 >> 6) & 15, d = f0 & 63;
        ushort4 o4;
        o4.x = f2bf(acc[mi][ni][0] * sc);
        o4.y = f2bf(acc[mi][ni][1] * sc);
        o4.z = f2bf(acc[mi][ni][2] * sc);
        o4.w = f2bf(acc[mi][ni][3] * sc);
        *(ushort4*)&base[((size_t)(b * 16 + h) * SEQ + n) * 64 + d] = o4;
      }
    }
  } else {
    // normal frags: row=quad*4+r -> token, col=l16 -> feature; V^T fp16
#pragma unroll
    for (int mi = 0; mi < 8; ++mi) {
      const int row = m0 + wm * 128 + mi * 16 + quad * 4;
      const int b = row >> 11, n = row & 2047;
#pragma unroll
      for (int ni = 0; ni < 4; ++ni) {
        const int col = n0 + wn * 64 + ni * 16 + l16;
        const int h = (col >> 6) & 15, d = col & 63;
        ushort4 o4;
        o4.x = f2h(acc[mi][ni][0]); o4.y = f2h(acc[mi][ni][1]);
        o4.z = f2h(acc[mi][ni][2]); o4.w = f2h(acc[mi][ni][3]);
        *(ushort4*)&vtb[((size_t)(b * 16 + h) * 64 + d) * SEQ + n] = o4;
      }
    }
  }
}

// ---- 8-phase 128x256 GEMM (V-gemm and proj): BM=128, BN=256, BK=64, 512
// threads (2m x 4n waves), per-wave 64x64 output (acc[4][4]). LDS 96KB,
// grid 4x64 = 256 blocks = one clean round. vmcnt(4) once per tile.
// EPI=0: V^T fp16 [bh][d][n] writes.  EPI=1: fp32 out + bias.
template<int EPI>
__global__ __launch_bounds__(512, 2) void gemm8_128x256(
    const unsigned short* __restrict__ A,    // [8192][1024] bf16
    const unsigned short* __restrict__ W,    // [1024][1024] bf16 (pre-offset)
    unsigned short* __restrict__ vtb,        // EPI=0
    float* __restrict__ outp,                // EPI=1
    const float* __restrict__ bias) {        // EPI=1
  constexpr int K = DIM;
  constexpr int NT = K / 64;                 // 16 K-tiles
  __shared__ unsigned short Al[2][128 * 64]; // 32KB
  __shared__ unsigned short Bl[2][256 * 64]; // 64KB

  const int tid  = threadIdx.x;
  const int wave = tid >> 6, lane = tid & 63;
  const int quad = lane >> 4, l16 = lane & 15;
  const int wm = wave >> 2, wn = wave & 3;   // 2 x 4 wave grid

  // XCD-bijective swizzle, nwg = 256
  int id = blockIdx.y * 4 + blockIdx.x;
  id = (id & 7) * 32 + (id >> 3);
  const int bx = id & 3, by = id >> 2;
  const int m0 = by * 128, n0 = bx * 256;

  const int srow8 = lane >> 3;               // 0..7
  const int schk  = (lane & 7) ^ srow8;      // pre-swizzled source chunk
  const unsigned short* Ast = A + (size_t)(m0 + srow8) * K + (schk << 3);
  const unsigned short* Bst = W + (size_t)(n0 + srow8) * K + (schk << 3);

  // pair-stage: waves 0-3 cover rows [R0,R0+32), waves 4-7 [R1,R1+32)
  auto stgA = [&](int kt, unsigned short* l, int R0, int R1) {
    const int rs = (wave < 4 ? R0 : R1) + (wave & 3) * 8;
    gload_lds16((const void*)(Ast + (size_t)rs * K + kt), (void*)(l + rs * 64));
  };
  auto stgB = [&](int kt, unsigned short* l, int R0, int R1) {
    const int rs = (wave < 4 ? R0 : R1) + (wave & 3) * 8;
    gload_lds16((const void*)(Bst + (size_t)rs * K + kt), (void*)(l + rs * 64));
  };
  auto ldf = [&](const unsigned short* base, int rb, int idx, int kk) -> bf16x8 {
    const int r = rb + idx * 16 + l16;
    return *(const bf16x8*)&base[r * 64 + (((kk * 4 + quad) ^ (l16 & 7)) << 3)];
  };

  f32x4 acc[4][4];
#pragma unroll
  for (int i = 0; i < 4; ++i)
#pragma unroll
    for (int j = 0; j < 4; ++j) acc[i][j] = (f32x4)0.f;

  // prologue: tile0 complete (6, oldest), tile1's t+2-set (4)
  stgA(0, Al[0], 0, 64);   stgA(0, Al[0], 32, 96);
  stgB(0, Bl[0], 0, 64);   stgB(0, Bl[0], 32, 96);
  stgB(0, Bl[0], 128, 192); stgB(0, Bl[0], 160, 224);
  stgA(64, Al[1], 0, 64);  stgA(64, Al[1], 32, 96);
  stgB(64, Bl[1], 0, 64);  stgB(64, Bl[1], 32, 96);
  asm volatile("s_waitcnt vmcnt(4)" ::: "memory");  // tile 0 landed
  __builtin_amdgcn_s_barrier();

  bf16x8 af[2][2], bf[4][2];
  int buf = 0;
  for (int t = 0; t < NT; ++t, buf ^= 1) {
    const unsigned short* Ac = Al[buf];
    const unsigned short* Bc = Bl[buf];
    unsigned short* Asg = Al[buf];
    unsigned short* Bsg = Bl[buf];
    const int kt2 = (t + 2) * 64;

    // ---------- P1: af(mi01)+bf(ni01) | stg B-hi(t+1) | mfma mi01 x ni01 ----
#pragma unroll
    for (int i = 0; i < 2; ++i) {
      af[i][0] = ldf(Ac, wm * 64, i, 0);
      af[i][1] = ldf(Ac, wm * 64, i, 1);
    }
#pragma unroll
    for (int ni = 0; ni < 2; ++ni) {
      bf[ni][0] = ldf(Bc, wn * 64, ni, 0);
      bf[ni][1] = ldf(Bc, wn * 64, ni, 1);
    }
    if (t + 1 < NT) {
      stgB((t + 1) * 64, Bl[buf ^ 1], 128, 192);
      stgB((t + 1) * 64, Bl[buf ^ 1], 160, 224);
    }
    __builtin_amdgcn_s_barrier();
    asm volatile("s_waitcnt lgkmcnt(0)" ::: "memory");
    __builtin_amdgcn_s_setprio(1);
#pragma unroll
    for (int mi = 0; mi < 2; ++mi)
#pragma unroll
      for (int ni = 0; ni < 2; ++ni)
#pragma unroll
        for (int kk = 0; kk < 2; ++kk)
          acc[mi][ni] = mm<0>(af[mi][kk], bf[ni][kk], acc[mi][ni]);
    __builtin_amdgcn_s_setprio(0);
    __builtin_amdgcn_s_barrier();

    // ---------- P2: bf(ni23) | stg A0(t+2) | mfma mi01 x ni23 ----
#pragma unroll
    for (int ni = 2; ni < 4; ++ni) {
      bf[ni][0] = ldf(Bc, wn * 64, ni, 0);
      bf[ni][1] = ldf(Bc, wn * 64, ni, 1);
    }
    if (t + 2 < NT) stgA(kt2, Asg, 0, 64);
    __builtin_amdgcn_s_barrier();
    asm volatile("s_waitcnt lgkmcnt(0)" ::: "memory");
    __builtin_amdgcn_s_setprio(1);
#pragma unroll
    for (int mi = 0; mi < 2; ++mi)
#pragma unroll
      for (int ni = 2; ni < 4; ++ni)
#pragma unroll
        for (int kk = 0; kk < 2; ++kk)
          acc[mi][ni] = mm<0>(af[mi][kk], bf[ni][kk], acc[mi][ni]);
    __builtin_amdgcn_s_setprio(0);
    __builtin_amdgcn_s_barrier();

    // ---------- P3: af(mi23) | stg B-lo(t+2) | mfma mi23 x ni23 ----
#pragma unroll
    for (int i = 0; i < 2; ++i) {
      af[i][0] = ldf(Ac, wm * 64, i + 2, 0);
      af[i][1] = ldf(Ac, wm * 64, i + 2, 1);
    }
    if (t + 2 < NT) {
      stgB(kt2, Bsg, 0, 64);
      stgB(kt2, Bsg, 32, 96);
    }
    __builtin_amdgcn_s_barrier();
    asm volatile("s_waitcnt lgkmcnt(0)" ::: "memory");
    __builtin_amdgcn_s_setprio(1);
#pragma unroll
    for (int mi = 0; mi < 2; ++mi)
#pragma unroll
      for (int ni = 2; ni < 4; ++ni)
#pragma unroll
        for (int kk = 0; kk < 2; ++kk)
          acc[mi + 2][ni] = mm<0>(af[mi][kk], bf[ni][kk], acc[mi + 2][ni]);
    __builtin_amdgcn_s_setprio(0);
    __builtin_amdgcn_s_barrier();

    // ---------- P4: stg A1(t+2) + vmcnt | mfma mi23 x ni01 ----
    if (t + 2 < NT) {
      stgA(kt2, Asg, 32, 96);
      asm volatile("s_waitcnt vmcnt(4)" ::: "memory");  // tile t+1 landed
    } else {
      asm volatile("s_waitcnt vmcnt(0)" ::: "memory");
    }
    __builtin_amdgcn_s_barrier();
    __builtin_amdgcn_s_setprio(1);
#pragma unroll
    for (int mi = 0; mi < 2; ++mi)
#pragma unroll
      for (int ni = 0; ni < 2; ++ni)
#pragma unroll
        for (int kk = 0; kk < 2; ++kk)
          acc[mi + 2][ni] = mm<0>(af[mi][kk], bf[ni][kk], acc[mi + 2][ni]);
    __builtin_amdgcn_s_setprio(0);
    __builtin_amdgcn_s_barrier();
  }

  // ---------- epilogue: normal frags, row=quad*4+r token, col=l16 ----
  if constexpr (EPI == 0) {
#pragma unroll
    for (int mi = 0; mi < 4; ++mi) {
      const int row = m0 + wm * 64 + mi * 16 + quad * 4;
      const int b = row >> 11, n = row & 2047;
#pragma unroll
      for (int ni = 0; ni < 4; ++ni) {
        const int col = n0 + wn * 64 + ni * 16 + l16;
        const int h = (col >> 6) & 15, d = col & 63;
        ushort4 o4;
        o4.x = f2h(acc[mi][ni][0]); o4.y = f2h(acc[mi][ni][1]);
        o4.z = f2h(acc[mi][ni][2]); o4.w = f2h(acc[mi][ni][3]);
        *(ushort4*)&vtb[((size_t)(b * 16 + h) * 64 + d) * SEQ + n] = o4;
      }
    }
  } else {
    // fp32 out + bias
#pragma unroll
    for (int mi = 0; mi < 4; ++mi) {
      const int row = m0 + wm * 64 + mi * 16 + quad * 4;
#pragma unroll
      for (int ni = 0; ni < 4; ++ni) {
        const int col = n0 + wn * 64 + ni * 16 + l16;
        const float bv = bias[col];
#pragma unroll
        for (int r = 0; r < 4; ++r)
          outp[(size_t)(row + r) * DIM + col] = acc[mi][ni][r] + bv;
      }
    }
  }
}

// ---- flash attention R11: 128-key double-tile per iteration.
// Same fragment math as R10 (kk now 0..3), but barriers HALVED: 16 iters of
// 128 keys instead of 32 of 64. Rationale: waves are phase-locked by the
// per-iter barrier (convoy: matrix pipe idles during the exp windows);
// halving barrier events and doubling per-phase work raises pipe overlap.
// 2 double-buffers (K 32KB + V 32KB = 64KB) keep 2 blocks/CU (16 waves/CU)
// so cross-block overlap still masks intra-block convoys (the 3-buffer/96KB
// variant would drop to 1 block/CU -- rejected).
// Sync per iter: vmcnt(0) [stage(t) is the ONLY outstanding; window = one
// full 128-key iteration >> L2 latency, so the drain is free] -> barrier
// [publishes tile t AND retires all reads of buf[(t+1)&1] from iter t-1]
// -> stage(t+1) into buf[(t+1)&1]. setprio around MFMA clusters kept.
// Swizzle algebra extends to kk<4: K rows R=kk*32+8a+b+4T keep R&3=b and
// (R>>3)&1=a&1 (kk*4 even); V chunk XOR touches only low 3 bits of the
// 4-bit chunk index, write/read involution unchanged.
__global__ __launch_bounds__(512, 2) void attn_kernel(
    const unsigned short* __restrict__ qb,   // [bh][n][d] bf16, pre-scaled by QSCALE
    const unsigned short* __restrict__ kb,   // [bh][n][d] bf16
    const unsigned short* __restrict__ vtb,  // [bh][d][n] fp16
    unsigned short* __restrict__ out) {      // [8192][1024] bf16
  __shared__ unsigned short Kl[2][128 * 64]; // [key 0..127][d], 128B rows, 32KB
  __shared__ unsigned short Vl[2][64 * 128]; // [d 0..63][key 0..127], 256B rows, 32KB

  const int tid  = threadIdx.x;
  const int wave = tid >> 6, lane = tid & 63;
  const int quad = lane >> 4, l16 = lane & 15;
  const int bh    = blockIdx.x;           // 0..63  (XCD affinity)
  const int qtile = blockIdx.y;           // 0..7
  const size_t qkbase = (size_t)bh * SEQ * 64;
  const int q0 = qtile * 256 + wave * 32;

  // Q B-frags: Q[n=l16][k=dk*32+quad*8+j]  (dk = d-half)
  bf16x8 qf[2][2];
#pragma unroll
  for (int mi = 0; mi < 2; mi++)
#pragma unroll
    for (int dk = 0; dk < 2; dk++)
      qf[mi][dk] = *(const bf16x8*)&qb[qkbase + (size_t)(q0 + mi * 16 + l16) * 64 + dk * 32 + quad * 8];

  f32x4 o[2][4];
#pragma unroll
  for (int mi = 0; mi < 2; mi++)
#pragma unroll
    for (int nt = 0; nt < 4; nt++) o[mi][nt] = (f32x4)0.f;
  f32x4 lacc[2];
#pragma unroll
  for (int mi = 0; mi < 2; mi++) lacc[mi] = (f32x4)0.f;

  union { f16x8 v; unsigned int d[4]; } ones8;
#pragma unroll
  for (int j = 0; j < 4; j++) ones8.d[j] = 0x3C003C00u;  // fp16 1.0 x8

  const unsigned short* Kg = kb + qkbase;
  const unsigned short* Vg = vtb + (size_t)bh * 64 * SEQ;
  // K staging: srow 0..63 per round (rounds p=0,1 -> rows p*64+srow)
  const int srow = tid >> 3;               // 0..63
  const int schk = tid & 7;                // 8 chunks per 128B K row
  const int swK = (srow & 3) | (((srow >> 3) & 1) << 2);  // == sR(read) for these rows
  // V staging: vrow 0..31 per round (d = p*32 + vrow), 16 chunks per 256B row
  const int vrow = tid >> 4;               // 0..31
  const int vchk = tid & 15;
  const int swV = vrow & 7;                // d&7 (p*32 preserves &7)

  auto stage = [&](int kt, int b) {
#pragma unroll
    for (int p = 0; p < 2; p++) {
      // K rows p*64 + 0..63
      gload_lds16((const void*)(Kg + (size_t)(kt + p * 64 + srow) * 64 + (schk ^ swK) * 8),
                  (void*)&Kl[b][(p * 64 + wave * 8) * 64]);
      // V d-rows p*32 + 0..31, 128 keys each
      gload_lds16((const void*)(Vg + (size_t)(p * 32 + vrow) * SEQ + kt + ((vchk ^ swV) << 3)),
                  (void*)&Vl[b][(p * 32 + wave * 4) * 128]);
    }
  };

  stage(0, 0);   // 4 loads/thread

  const int rbase = ((l16 >> 2) << 3) + (l16 & 3);               // 8a + b
  const int sR = (l16 & 3) | (((l16 >> 2) & 1) << 2);            // K read swizzle

  for (int t = 0; t < 16; ++t) {
    // stage(t) is the only outstanding set; window was a full iteration
    asm volatile("s_waitcnt vmcnt(0) lgkmcnt(0)" ::: "memory");
    __builtin_amdgcn_s_barrier();   // publish tile t; retire reads of buf[(t+1)&1]
    if (t + 1 < 16) stage((t + 1) * 128, (t + 1) & 1);

    const unsigned short* Kc = &Kl[t & 1][0];
    const unsigned short* Vc = &Vl[t & 1][0];

#pragma unroll
    for (int kk = 0; kk < 4; kk++) {
      // K A-frags, permuted rows: phys keys kk*32 + 8a + b + 4T
      bf16x8 kf[2][2];
#pragma unroll
      for (int T = 0; T < 2; T++) {
        const int R = kk * 32 + rbase + 4 * T;
        kf[T][0] = *(const bf16x8*)&Kc[R * 64 + ((quad ^ sR) << 3)];
        kf[T][1] = *(const bf16x8*)&Kc[R * 64 + (((4 + quad) ^ sR) << 3)];
      }
      // V B-frags: B[n=d=nt*16+l16][k=key=kk*32+quad*8+j]
      f16x8 vf[4];
#pragma unroll
      for (int nt = 0; nt < 4; nt++) {
        const int vr = nt * 16 + l16;
        vf[nt] = *(const f16x8*)&Vc[vr * 128 + (((kk * 4 + quad) ^ (vr & 7)) << 3)];
      }
      __builtin_amdgcn_s_setprio(1);
#pragma unroll
      for (int mi = 0; mi < 2; mi++) {
        // S^T tiles: C[m -> phys key kk*32+8*quad+r(+4T)][n=q=l16]
        f32x4 s0 = (f32x4)0.f, s1 = (f32x4)0.f;
        s0 = MFMA_BF16_K32(kf[0][0], qf[mi][0], s0);
        s0 = MFMA_BF16_K32(kf[0][1], qf[mi][1], s0);
        s1 = MFMA_BF16_K32(kf[1][0], qf[mi][0], s1);
        s1 = MFMA_BF16_K32(kf[1][1], qf[mi][1], s1);
        // P A-frag (16x16x32 f16): lane holds keys kk*32+quad*8+0..7 for q=l16
        union { f16x8 v; unsigned int d[4]; } pu;
        pu.d[0] = pkrtz_bits(EXP2F(s0[0]), EXP2F(s0[1]));
        pu.d[1] = pkrtz_bits(EXP2F(s0[2]), EXP2F(s0[3]));
        pu.d[2] = pkrtz_bits(EXP2F(s1[0]), EXP2F(s1[1]));
        pu.d[3] = pkrtz_bits(EXP2F(s1[2]), EXP2F(s1[3]));
        lacc[mi] = MFMA_F16_K32(pu.v, ones8.v, lacc[mi]);
#pragma unroll
        for (int nt = 0; nt < 4; nt++)
          o[mi][nt] = MFMA_F16_K32(pu.v, vf[nt], o[mi][nt]);
      }
      __builtin_amdgcn_s_setprio(0);
    }
  }

  const int h = bh & 15, b = bh >> 4;
#pragma unroll
  for (int mi = 0; mi < 2; mi++) {
    float inv[4];
#pragma unroll
    for (int r = 0; r < 4; r++) inv[r] = 1.f / lacc[mi][r];
#pragma unroll
    for (int nt = 0; nt < 4; nt++)
#pragma unroll
      for (int r = 0; r < 4; r++)
        out[((size_t)(b * SEQ + q0 + mi * 16 + quad * 4 + r)) * DIM + h * 64 + nt * 16 + l16] =
            f2bf(o[mi][nt][r] * inv[r]);
  }
}

extern "C" void kernel_launch(void* const* d_in, const int* in_sizes, int n_in,
                              void* d_out, int out_size, void* d_ws, size_t ws_size,
                              hipStream_t stream) {
  const float* x      = (const float*)d_in[0];
  const float* w_qkv  = (const float*)d_in[1];
  const float* w_proj = (const float*)d_in[2];
  const float* b_proj = (const float*)d_in[3];
  float* outp = (float*)d_out;

  char* ws = (char*)d_ws;
  unsigned short* xb     = (unsigned short*)(ws);                        // 16 MB
  unsigned short* wqkvb  = (unsigned short*)(ws + (16u << 20));          // 6 MB
  unsigned short* wprojb = (unsigned short*)(ws + (22u << 20));          // 2 MB
  unsigned short* qb     = (unsigned short*)(ws + (24u << 20));          // 16 MB
  unsigned short* kb     = (unsigned short*)(ws + (40u << 20));          // 16 MB
  unsigned short* vtb    = (unsigned short*)(ws + (56u << 20));          // 16 MB (fp16)
  unsigned short* aout   = (unsigned short*)(ws + (72u << 20));          // 16 MB

  const int total4 = (ROWS * DIM + 3 * DIM * DIM + DIM * DIM) / 4;  // 3,145,728
  cast_all<<<total4 / 256, 256, 0, stream>>>(x, w_qkv, w_proj, xb, wqkvb, wprojb);

  gemm_qkv8<1, 8><<<dim3(8, 32), 512, 0, stream>>>(xb, wqkvb, qb, kb, vtb);  // Q,K
  gemm8_128x256<0><<<dim3(4, 64), 512, 0, stream>>>(
      xb, wqkvb + (size_t)2048 * DIM, vtb, nullptr, nullptr);               // V
  attn_kernel<<<dim3(64, 8), 512, 0, stream>>>(qb, kb, vtb, aout);
  gemm8_128x256<1><<<dim3(4, 64), 512, 0, stream>>>(
      aout, wprojb, nullptr, outp, b_proj);                                 // proj
}

// Round 7
// 256.633 us; speedup vs baseline: 1.0070x; 1.0070x over previous
//
#include <hip/hip_runtime.h>
#include <stdint.h>

#define DIM 1024
#define SEQ 2048
#define BATCH 4
#define ROWS (BATCH*SEQ)          /* 8192 */
// attention scale folded into Q: 0.125 * log2(e)
#define QSCALE 0.1803368801111f

typedef __attribute__((ext_vector_type(8))) short bf16x8;   // 8 bf16 in 4 VGPRs
typedef __attribute__((ext_vector_type(4))) float f32x4;
typedef __attribute__((ext_vector_type(8))) _Float16 f16x8;
typedef __attribute__((ext_vector_type(2))) __fp16 fp16x2_raw;  // cvt_pkrtz return type

#if __has_builtin(__builtin_amdgcn_exp2f)
#define EXP2F(x) __builtin_amdgcn_exp2f(x)
#else
#define EXP2F(x) __expf((x) * 0.69314718056f)
#endif

#define MFMA_BF16_K32(a,b,c) __builtin_amdgcn_mfma_f32_16x16x32_bf16(a,b,c,0,0,0)
#define MFMA_F16_K32(a,b,c)  __builtin_amdgcn_mfma_f32_16x16x32_f16(a,b,c,0,0,0)

// ---- fp32 -> bf16 RNE ----
__device__ __forceinline__ unsigned short f2bf(float f) {
  union { float f; unsigned int u; } v; v.f = f;
  unsigned int u = v.u;
  return (unsigned short)((u + 0x7FFFu + ((u >> 16) & 1u)) >> 16);
}

// ---- fp32 -> fp16 RNE (bits) ----
__device__ __forceinline__ unsigned short f2h(float f) {
  union { _Float16 h; unsigned short u; } v;
  v.h = (_Float16)f;
  return v.u;
}

// pack two f32 -> fp16x2 dword (v_cvt_pkrtz_f16_f32), returned as raw bits
__device__ __forceinline__ unsigned int pkrtz_bits(float lo, float hi) {
  union { fp16x2_raw h; unsigned int u; } v;
  v.h = __builtin_amdgcn_cvt_pkrtz(lo, hi);
  return v.u;
}

// ---- async global->LDS, 16B per lane (wave-uniform LDS base + lane*16) ----
__device__ __forceinline__ void gload_lds16(const void* g, void* l) {
  __builtin_amdgcn_global_load_lds(
      (const __attribute__((address_space(1))) unsigned int*)g,
      (__attribute__((address_space(3))) unsigned int*)l,
      16, 0, 0);
}

// ---- fused cast kernel: x (8M) | w_qkv (3M) | w_proj (1M) fp32 -> bf16 ----
__global__ void cast_all(const float* __restrict__ x,
                         const float* __restrict__ wq,
                         const float* __restrict__ wp,
                         unsigned short* __restrict__ xb,
                         unsigned short* __restrict__ wqb,
                         unsigned short* __restrict__ wpb) {
  const int i = (blockIdx.x * blockDim.x + threadIdx.x) * 4;
  const float* src;
  unsigned short* dst;
  int off;
  if (i < ROWS * DIM)                 { src = x;  dst = xb;  off = i; }
  else if (i < ROWS * DIM + 3 * DIM * DIM) { src = wq; dst = wqb; off = i - ROWS * DIM; }
  else                                { src = wp; dst = wpb; off = i - ROWS * DIM - 3 * DIM * DIM; }
  float4 f = *(const float4*)(src + off);
  ushort4 o;
  o.x = f2bf(f.x); o.y = f2bf(f.y); o.z = f2bf(f.z); o.w = f2bf(f.w);
  *(ushort4*)(dst + off) = o;
}

// ---- QKV GEMM (R0 monolith + LDS conflict fix): C[8192,3072] = X @ Wqkv^T.
// 128x128 tile, BK=32, 256 threads, 2-phase. R0 measured 75us/687TF with
// 6.29M LDS bank conflicts: 64B rows + fixed chunk-per-quad => within each
// 16-lane b128 phase all lanes hit one 16B chunk column -> 8-way conflict.
// FIX (both-sides, rule #21): chunk ^= (row>>1)&3. Write side: gload_lds is
// linear, so pre-swizzle the GLOBAL source chunk: src_chunk = (lane&3) ^
// ((lane>>3)&3)  [staging row = wave*16 + (lane>>2) (+64i), so (row>>1)&3 =
// (lane>>3)&3]. Read side: chunk = quad ^ ((l16>>1)&3) [frag row = wr/wc +
// i*16 + l16, low 4 bits = l16]. Banks per 16-lane phase: (l16&1)*16 +
// (quad^((l16>>1)&3))*4 -> 8 distinct 4-bank groups x 2 lanes = free.
__global__ __launch_bounds__(256) void gemm_qkv(
    const unsigned short* __restrict__ A,
    const unsigned short* __restrict__ W,
    unsigned short* __restrict__ qb,
    unsigned short* __restrict__ kb,
    unsigned short* __restrict__ vtb) {
  const int K = DIM;
  __shared__ unsigned short Al[128 * 32];
  __shared__ unsigned short Wl[128 * 32];
  const int tid  = threadIdx.x;
  const int wave = tid >> 6, lane = tid & 63;
  const int quad = lane >> 4, l16 = lane & 15;
  const int m0 = blockIdx.y * 128, n0 = blockIdx.x * 128;
  const int wr = (wave >> 1) * 64, wc = (wave & 1) * 64;
  const int which = n0 >> 10;  // 0=Q, 1=K, 2=V (uniform per block)

  f32x4 acc[4][4];
#pragma unroll
  for (int i = 0; i < 4; i++)
#pragma unroll
    for (int j = 0; j < 4; j++) acc[i][j] = (f32x4)0.f;

  const int arow = wave * 16 + (lane >> 2);
  // pre-swizzled source chunk: (lane&3) ^ ((row>>1)&3), row low bits = lane>>2
  const int acol = ((lane & 3) ^ ((lane >> 3) & 3)) * 8;
  const unsigned short* Ag = A + (size_t)(m0 + arow) * K + acol;
  const unsigned short* Wg = W + (size_t)(n0 + arow) * K + acol;
  const int sA = (l16 >> 1) & 3;   // read-side row swizzle ((row>>1)&3)

  if (which < 2) {
    for (int kt = 0; kt < K; kt += 32) {
      __syncthreads();
#pragma unroll
      for (int i = 0; i < 2; i++) {
        gload_lds16((const void*)(Ag + (size_t)(i * 64) * K + kt), (void*)&Al[i * 2048 + wave * 512]);
        gload_lds16((const void*)(Wg + (size_t)(i * 64) * K + kt), (void*)&Wl[i * 2048 + wave * 512]);
      }
      __syncthreads();
      bf16x8 af[4], wf[4];
#pragma unroll
      for (int i = 0; i < 4; i++) {
        af[i] = *(const bf16x8*)&Al[(wr + i * 16 + l16) * 32 + ((quad ^ sA) << 3)];
        wf[i] = *(const bf16x8*)&Wl[(wc + i * 16 + l16) * 32 + ((quad ^ sA) << 3)];
      }
#pragma unroll
      for (int i = 0; i < 4; i++)
#pragma unroll
        for (int j = 0; j < 4; j++)
          acc[i][j] = __builtin_amdgcn_mfma_f32_16x16x32_bf16(wf[j], af[i], acc[i][j], 0, 0, 0);
    }
    // epilogue (transposed frag): row=quad*4+r -> feature, col=l16 -> token
    const float sc = (which == 0) ? QSCALE : 1.f;
    unsigned short* base = (which == 0) ? qb : kb;
#pragma unroll
    for (int i = 0; i < 4; i++) {
      const int tok = m0 + wr + i * 16 + l16;
      const int b = tok >> 11, n = tok & 2047;
#pragma unroll
      for (int j = 0; j < 4; j++) {
        const int col0 = n0 + wc + j * 16 + quad * 4;
        const int h = (col0 >> 6) & 15, d = col0 & 63;
        ushort4 o4;
        o4.x = f2bf(acc[i][j][0] * sc); o4.y = f2bf(acc[i][j][1] * sc);
        o4.z = f2bf(acc[i][j][2] * sc); o4.w = f2bf(acc[i][j][3] * sc);
        *(ushort4*)&base[((size_t)(b * 16 + h) * SEQ + n) * 64 + d] = o4;
      }
    }
  } else {
    for (int kt = 0; kt < K; kt += 32) {
      __syncthreads();
#pragma unroll
      for (int i = 0; i < 2; i++) {
        gload_lds16((const void*)(Ag + (size_t)(i * 64) * K + kt), (void*)&Al[i * 2048 + wave * 512]);
        gload_lds16((const void*)(Wg + (size_t)(i * 64) * K + kt), (void*)&Wl[i * 2048 + wave * 512]);
      }
      __syncthreads();
      bf16x8 af[4], wf[4];
#pragma unroll
      for (int i = 0; i < 4; i++) {
        af[i] = *(const bf16x8*)&Al[(wr + i * 16 + l16) * 32 + ((quad ^ sA) << 3)];
        wf[i] = *(const bf16x8*)&Wl[(wc + i * 16 + l16) * 32 + ((quad ^ sA) << 3)];
      }
#pragma unroll
      for (int i = 0; i < 4; i++)
#pragma unroll
        for (int j = 0; j < 4; j++)
          acc[i][j] = __builtin_amdgcn_mfma_f32_16x16x32_bf16(af[i], wf[j], acc[i][j], 0, 0, 0);
    }
    // epilogue (normal frag): 4 consecutive tokens per lane -> V^T fp16 ushort4
#pragma unroll
    for (int i = 0; i < 4; i++) {
      const int row = m0 + wr + i * 16 + quad * 4;
      const int b = row >> 11, n = row & 2047;
#pragma unroll
      for (int j = 0; j < 4; j++) {
        const int col = n0 + wc + j * 16 + l16;
        const int h = (col >> 6) & 15, d = col & 63;
        ushort4 o4;
        o4.x = f2h(acc[i][j][0]); o4.y = f2h(acc[i][j][1]);
        o4.z = f2h(acc[i][j][2]); o4.w = f2h(acc[i][j][3]);
        *(ushort4*)&vtb[((size_t)(b * 16 + h) * 64 + d) * SEQ + n] = o4;
      }
    }
  }
}

// ---- flash attention (R10, proven 69.96us) + tightened T5 setprio:
// prio 1 ONLY around MFMA clusters; drop to 0 during the exp/pkrtz chain so
// a wave doing trans ops doesn't starve other waves' MFMA issue (T5 recipe:
// MFMA clusters only). Everything else identical to R10: LDS staging with
// 8-wave K/V sharing, 3 rotating buffers, prefetch distance 2, per-iter
// "s_waitcnt vmcnt(2) lgkmcnt(0); s_barrier" (2 newest gloads stay in
// flight across the barrier; waitcnt-then-barrier order REQUIRED for
// cooperative staging visibility). Tail drains vmcnt(0). 48KB, 2 blk/CU.
__global__ __launch_bounds__(512, 4) void attn_kernel(
    const unsigned short* __restrict__ qb,   // [bh][n][d] bf16, pre-scaled by QSCALE
    const unsigned short* __restrict__ kb,   // [bh][n][d] bf16
    const unsigned short* __restrict__ vtb,  // [bh][d][n] fp16
    unsigned short* __restrict__ out) {      // [8192][1024] bf16
  __shared__ unsigned short Kl[3][64 * 64];  // [key][d], chunk c at c^sK(row)
  __shared__ unsigned short Vl[3][64 * 64];  // [d][key] fp16 bits, chunk c at c^(row&7)

  const int tid  = threadIdx.x;
  const int wave = tid >> 6, lane = tid & 63;
  const int quad = lane >> 4, l16 = lane & 15;
  const int bh    = blockIdx.x;           // 0..63  (XCD affinity)
  const int qtile = blockIdx.y;           // 0..7
  const size_t qkbase = (size_t)bh * SEQ * 64;
  const int q0 = qtile * 256 + wave * 32;

  // Q B-frags: Q[n=l16][k=kk*32+quad*8+j]  (kk = d-half here)
  bf16x8 qf[2][2];
#pragma unroll
  for (int mi = 0; mi < 2; mi++)
#pragma unroll
    for (int kk = 0; kk < 2; kk++)
      qf[mi][kk] = *(const bf16x8*)&qb[qkbase + (size_t)(q0 + mi * 16 + l16) * 64 + kk * 32 + quad * 8];

  f32x4 o[2][4];
#pragma unroll
  for (int mi = 0; mi < 2; mi++)
#pragma unroll
    for (int nt = 0; nt < 4; nt++) o[mi][nt] = (f32x4)0.f;
  f32x4 lacc[2];
#pragma unroll
  for (int mi = 0; mi < 2; mi++) lacc[mi] = (f32x4)0.f;

  union { f16x8 v; unsigned int d[4]; } ones8;
#pragma unroll
  for (int j = 0; j < 4; j++) ones8.d[j] = 0x3C003C00u;  // fp16 1.0 x8

  const unsigned short* Kg = kb + qkbase;
  const unsigned short* Vg = vtb + (size_t)bh * 64 * SEQ;
  const int srow = tid >> 3;   // 0..63 (512 threads cover 64 rows)
  const int schk = tid & 7;
  const int swK = (srow & 3) | (((srow >> 3) & 1) << 2);
  const int swV = srow & 7;

  auto stage = [&](int kt, int b) {
    gload_lds16((const void*)(Kg + (size_t)(kt + srow) * 64 + (schk ^ swK) * 8),
                (void*)&Kl[b][wave * 512]);
    gload_lds16((const void*)(Vg + (size_t)srow * SEQ + kt + (schk ^ swV) * 8),
                (void*)&Vl[b][wave * 512]);
  };

  stage(0, 0);    // 2 loads/thread
  stage(64, 1);   // 2 loads/thread

  const int rbase = ((l16 >> 2) << 3) + (l16 & 3);               // 8a + b
  const int sR = (l16 & 3) | (((l16 >> 2) & 1) << 2);            // K read swizzle

  int b0 = 0, b1 = 1, b2 = 2;
  for (int t = 0; t < 32; ++t) {
    // tile t landed; stage(t+1)'s 2 loads stay in flight across the barrier
    if (t < 31) asm volatile("s_waitcnt vmcnt(2) lgkmcnt(0)" ::: "memory");
    else        asm volatile("s_waitcnt vmcnt(0) lgkmcnt(0)" ::: "memory");
    __builtin_amdgcn_s_barrier();
    if (t + 2 < 32) stage((t + 2) * 64, b2);  // b2 = buffer read at iter t-1

    const unsigned short* Kc = &Kl[b0][0];
    const unsigned short* Vc = &Vl[b0][0];

#pragma unroll
    for (int kk = 0; kk < 2; kk++) {
      // K A-frags, permuted rows: T gives phys keys kk*32 + 8*(l16>>2) + (l16&3) + 4T
      bf16x8 kf[2][2];
#pragma unroll
      for (int T = 0; T < 2; T++) {
        const int R = kk * 32 + rbase + 4 * T;
        kf[T][0] = *(const bf16x8*)&Kc[R * 64 + ((quad ^ sR) << 3)];
        kf[T][1] = *(const bf16x8*)&Kc[R * 64 + (((4 + quad) ^ sR) << 3)];
      }
      // V B-frags: B[n=d=nt*16+l16][k=key=kk*32+quad*8+j]
      f16x8 vf[4];
#pragma unroll
      for (int nt = 0; nt < 4; nt++) {
        const int vr = nt * 16 + l16;
        vf[nt] = *(const f16x8*)&Vc[vr * 64 + (((kk * 4 + quad) ^ (vr & 7)) << 3)];
      }
#pragma unroll
      for (int mi = 0; mi < 2; mi++) {
        // S^T tiles: C[m -> phys key kk*32+8*quad+r(+4T)][n=q=l16]
        f32x4 s0 = (f32x4)0.f, s1 = (f32x4)0.f;
        __builtin_amdgcn_s_setprio(1);
        s0 = MFMA_BF16_K32(kf[0][0], qf[mi][0], s0);
        s0 = MFMA_BF16_K32(kf[0][1], qf[mi][1], s0);
        s1 = MFMA_BF16_K32(kf[1][0], qf[mi][0], s1);
        s1 = MFMA_BF16_K32(kf[1][1], qf[mi][1], s1);
        __builtin_amdgcn_s_setprio(0);
        // P A-frag (16x16x32 f16): exp chain at prio 0 (don't starve MFMA waves)
        union { f16x8 v; unsigned int d[4]; } pu;
        pu.d[0] = pkrtz_bits(EXP2F(s0[0]), EXP2F(s0[1]));
        pu.d[1] = pkrtz_bits(EXP2F(s0[2]), EXP2F(s0[3]));
        pu.d[2] = pkrtz_bits(EXP2F(s1[0]), EXP2F(s1[1]));
        pu.d[3] = pkrtz_bits(EXP2F(s1[2]), EXP2F(s1[3]));
        __builtin_amdgcn_s_setprio(1);
        lacc[mi] = MFMA_F16_K32(pu.v, ones8.v, lacc[mi]);
#pragma unroll
        for (int nt = 0; nt < 4; nt++)
          o[mi][nt] = MFMA_F16_K32(pu.v, vf[nt], o[mi][nt]);
        __builtin_amdgcn_s_setprio(0);
      }
    }
    const int tmp = b0; b0 = b1; b1 = b2; b2 = tmp;
  }

  const int h = bh & 15, b = bh >> 4;
#pragma unroll
  for (int mi = 0; mi < 2; mi++) {
    float inv[4];
#pragma unroll
    for (int r = 0; r < 4; r++) inv[r] = 1.f / lacc[mi][r];
#pragma unroll
    for (int nt = 0; nt < 4; nt++)
#pragma unroll
      for (int r = 0; r < 4; r++)
        out[((size_t)(b * SEQ + q0 + mi * 16 + quad * 4 + r)) * DIM + h * 64 + nt * 16 + l16] =
            f2bf(o[mi][nt][r] * inv[r]);
  }
}

// ---- proj GEMM (R0 + same LDS conflict fix): out = Ao bf16 @ Wproj^T + b ----
__global__ __launch_bounds__(256) void gemm_proj(
    const unsigned short* __restrict__ A,
    const unsigned short* __restrict__ W,
    float* __restrict__ out,
    const float* __restrict__ bias) {
  const int N = DIM, K = DIM;
  __shared__ unsigned short Al[128 * 32];
  __shared__ unsigned short Wl[128 * 32];
  const int tid  = threadIdx.x;
  const int wave = tid >> 6, lane = tid & 63;
  const int quad = lane >> 4, l16 = lane & 15;
  const int m0 = blockIdx.y * 128, n0 = blockIdx.x * 128;
  const int wr = (wave >> 1) * 64, wc = (wave & 1) * 64;

  f32x4 acc[4][4];
#pragma unroll
  for (int i = 0; i < 4; i++)
#pragma unroll
    for (int j = 0; j < 4; j++) acc[i][j] = (f32x4)0.f;

  const int arow = wave * 16 + (lane >> 2);
  const int acol = ((lane & 3) ^ ((lane >> 3) & 3)) * 8;   // pre-swizzled source
  const unsigned short* Ag = A + (size_t)(m0 + arow) * K + acol;
  const unsigned short* Wg = W + (size_t)(n0 + arow) * K + acol;
  const int sA = (l16 >> 1) & 3;

  for (int kt = 0; kt < K; kt += 32) {
    __syncthreads();
#pragma unroll
    for (int i = 0; i < 2; i++) {
      gload_lds16((const void*)(Ag + (size_t)(i * 64) * K + kt), (void*)&Al[i * 2048 + wave * 512]);
      gload_lds16((const void*)(Wg + (size_t)(i * 64) * K + kt), (void*)&Wl[i * 2048 + wave * 512]);
    }
    __syncthreads();

    bf16x8 af[4], wf[4];
#pragma unroll
    for (int i = 0; i < 4; i++) {
      af[i] = *(const bf16x8*)&Al[(wr + i * 16 + l16) * 32 + ((quad ^ sA) << 3)];
      wf[i] = *(const bf16x8*)&Wl[(wc + i * 16 + l16) * 32 + ((quad ^ sA) << 3)];
    }
#pragma unroll
    for (int i = 0; i < 4; i++)
#pragma unroll
      for (int j = 0; j < 4; j++)
        acc[i][j] = __builtin_amdgcn_mfma_f32_16x16x32_bf16(af[i], wf[j], acc[i][j], 0, 0, 0);
  }

#pragma unroll
  for (int i = 0; i < 4; i++) {
    const int row = m0 + wr + i * 16 + quad * 4;
#pragma unroll
    for (int j = 0; j < 4; j++) {
      const int col = n0 + wc + j * 16 + l16;
      const float bv = bias[col];
#pragma unroll
      for (int r = 0; r < 4; r++)
        out[(size_t)(row + r) * N + col] = acc[i][j][r] + bv;
    }
  }
}

extern "C" void kernel_launch(void* const* d_in, const int* in_sizes, int n_in,
                              void* d_out, int out_size, void* d_ws, size_t ws_size,
                              hipStream_t stream) {
  const float* x      = (const float*)d_in[0];
  const float* w_qkv  = (const float*)d_in[1];
  const float* w_proj = (const float*)d_in[2];
  const float* b_proj = (const float*)d_in[3];
  float* outp = (float*)d_out;

  char* ws = (char*)d_ws;
  unsigned short* xb     = (unsigned short*)(ws);                        // 16 MB
  unsigned short* wqkvb  = (unsigned short*)(ws + (16u << 20));          // 6 MB
  unsigned short* wprojb = (unsigned short*)(ws + (22u << 20));          // 2 MB
  unsigned short* qb     = (unsigned short*)(ws + (24u << 20));          // 16 MB
  unsigned short* kb     = (unsigned short*)(ws + (40u << 20));          // 16 MB
  unsigned short* vtb    = (unsigned short*)(ws + (56u << 20));          // 16 MB (fp16)
  unsigned short* aout   = (unsigned short*)(ws + (72u << 20));          // 16 MB

  const int total4 = (ROWS * DIM + 3 * DIM * DIM + DIM * DIM) / 4;  // 3,145,728
  cast_all<<<total4 / 256, 256, 0, stream>>>(x, w_qkv, w_proj, xb, wqkvb, wprojb);

  gemm_qkv<<<dim3(24, 64), 256, 0, stream>>>(xb, wqkvb, qb, kb, vtb);
  attn_kernel<<<dim3(64, 8), 512, 0, stream>>>(qb, kb, vtb, aout);
  gemm_proj<<<dim3(8, 64), 256, 0, stream>>>(aout, wprojb, outp, b_proj);
}

// Round 13
// 245.941 us; speedup vs baseline: 1.0508x; 1.0435x over previous
//
#include <hip/hip_runtime.h>
#include <stdint.h>

#define DIM 1024
#define SEQ 2048
#define BATCH 4
#define ROWS (BATCH*SEQ)          /* 8192 */
// attention scale folded into Q: 0.125 * log2(e)
#define QSCALE 0.1803368801111f

typedef __attribute__((ext_vector_type(8))) short bf16x8;   // 8 bf16 in 4 VGPRs
typedef __attribute__((ext_vector_type(4))) float f32x4;
typedef __attribute__((ext_vector_type(8))) _Float16 f16x8;
typedef __attribute__((ext_vector_type(2))) __fp16 fp16x2_raw;  // cvt_pkrtz return type

#if __has_builtin(__builtin_amdgcn_exp2f)
#define EXP2F(x) __builtin_amdgcn_exp2f(x)
#else
#define EXP2F(x) __expf((x) * 0.69314718056f)
#endif

#define MFMA_BF16_K32(a,b,c) __builtin_amdgcn_mfma_f32_16x16x32_bf16(a,b,c,0,0,0)
#define MFMA_F16_K32(a,b,c)  __builtin_amdgcn_mfma_f32_16x16x32_f16(a,b,c,0,0,0)

// ---- fp32 -> bf16 RNE ----
__device__ __forceinline__ unsigned short f2bf(float f) {
  union { float f; unsigned int u; } v; v.f = f;
  unsigned int u = v.u;
  return (unsigned short)((u + 0x7FFFu + ((u >> 16) & 1u)) >> 16);
}

// ---- fp32 -> fp16 RNE (bits) ----
__device__ __forceinline__ unsigned short f2h(float f) {
  union { _Float16 h; unsigned short u; } v;
  v.h = (_Float16)f;
  return v.u;
}

// pack two f32 -> fp16x2 dword (v_cvt_pkrtz_f16_f32), returned as raw bits
__device__ __forceinline__ unsigned int pkrtz_bits(float lo, float hi) {
  union { fp16x2_raw h; unsigned int u; } v;
  v.h = __builtin_amdgcn_cvt_pkrtz(lo, hi);
  return v.u;
}

// ---- async global->LDS, 16B per lane (wave-uniform LDS base + lane*16) ----
__device__ __forceinline__ void gload_lds16(const void* g, void* l) {
  __builtin_amdgcn_global_load_lds(
      (const __attribute__((address_space(1))) unsigned int*)g,
      (__attribute__((address_space(3))) unsigned int*)l,
      16, 0, 0);
}

// ---- fused cast kernel: x (8M) | w_qkv (3M) | w_proj (1M) fp32 -> bf16 ----
__global__ void cast_all(const float* __restrict__ x,
                         const float* __restrict__ wq,
                         const float* __restrict__ wp,
                         unsigned short* __restrict__ xb,
                         unsigned short* __restrict__ wqb,
                         unsigned short* __restrict__ wpb) {
  const int i = (blockIdx.x * blockDim.x + threadIdx.x) * 4;
  const float* src;
  unsigned short* dst;
  int off;
  if (i < ROWS * DIM)                 { src = x;  dst = xb;  off = i; }
  else if (i < ROWS * DIM + 3 * DIM * DIM) { src = wq; dst = wqb; off = i - ROWS * DIM; }
  else                                { src = wp; dst = wpb; off = i - ROWS * DIM - 3 * DIM * DIM; }
  float4 f = *(const float4*)(src + off);
  ushort4 o;
  o.x = f2bf(f.x); o.y = f2bf(f.y); o.z = f2bf(f.z); o.w = f2bf(f.w);
  *(ushort4*)(dst + off) = o;
}

// ---- QKV GEMM (R7 monolith, BK 32->64): C[8192,3072] = X @ Wqkv^T.
// 128x128 tile, 256 threads, 2-phase, 16 K-iters of BK=64 (was 32 of 32).
// R7 measured: conflicts 0, MfmaUtil 28.7%, 73.8us -- the residual stall is
// the per-iter {drain-all + 2 barriers} (m233: 2-phase critical path). That
// stall is ~constant per iteration, so BK=64 doubles MFMA work per barrier
// event (32 MFMA/iter) and halves iteration count: barrier overhead share
// ~halves. Frags loaded per-kk (kk=0,1) so live registers unchanged.
// LDS 32KB (2 tiles of 128x64), still >=4 blocks/CU at ~76 VGPR.
// Swizzle for 128B rows (8 chunks), both-sides involution chunk ^= row&7:
//   write: gload_lds linear dest; source chunk = (lane&7) ^ ((lane>>3)&7)
//          [staging row = i*32 + wave*8 + (lane>>3) => row&7 = (lane>>3)&7]
//   read:  chunk = ((kk<<2)|quad) ^ (l16&7)  [frag row&7 = l16&7]
//   banks: lanes 0-7 hit 8 distinct 4-bank groups; lanes 8-15 alias 2-way
//   (same bank, +1KB) = free (m136).
__global__ __launch_bounds__(256) void gemm_qkv(
    const unsigned short* __restrict__ A,
    const unsigned short* __restrict__ W,
    unsigned short* __restrict__ qb,
    unsigned short* __restrict__ kb,
    unsigned short* __restrict__ vtb) {
  const int K = DIM;
  __shared__ unsigned short Al[128 * 64];
  __shared__ unsigned short Wl[128 * 64];
  const int tid  = threadIdx.x;
  const int wave = tid >> 6, lane = tid & 63;
  const int quad = lane >> 4, l16 = lane & 15;
  const int m0 = blockIdx.y * 128, n0 = blockIdx.x * 128;
  const int wr = (wave >> 1) * 64, wc = (wave & 1) * 64;
  const int which = n0 >> 10;  // 0=Q, 1=K, 2=V (uniform per block)

  f32x4 acc[4][4];
#pragma unroll
  for (int i = 0; i < 4; i++)
#pragma unroll
    for (int j = 0; j < 4; j++) acc[i][j] = (f32x4)0.f;

  // staging: round i covers rows i*32 + wave*8 + (lane>>3), 8 chunks/row
  const int srow = wave * 8 + (lane >> 3);             // 0..31 within round
  const int schk = (lane & 7) ^ ((lane >> 3) & 7);     // pre-swizzled source
  const unsigned short* Ag = A + (size_t)(m0 + srow) * K + (schk << 3);
  const unsigned short* Wg = W + (size_t)(n0 + srow) * K + (schk << 3);
  const int sA = l16 & 7;                              // read-side row&7

  if (which < 2) {
    for (int kt = 0; kt < K; kt += 64) {
      __syncthreads();
#pragma unroll
      for (int i = 0; i < 4; i++) {
        gload_lds16((const void*)(Ag + (size_t)(i * 32) * K + kt), (void*)&Al[(i * 32 + wave * 8) * 64]);
        gload_lds16((const void*)(Wg + (size_t)(i * 32) * K + kt), (void*)&Wl[(i * 32 + wave * 8) * 64]);
      }
      __syncthreads();
#pragma unroll
      for (int kk = 0; kk < 2; kk++) {
        bf16x8 af[4], wf[4];
#pragma unroll
        for (int i = 0; i < 4; i++) {
          const int ck = (((kk << 2) | quad) ^ sA) << 3;
          af[i] = *(const bf16x8*)&Al[(wr + i * 16 + l16) * 64 + ck];
          wf[i] = *(const bf16x8*)&Wl[(wc + i * 16 + l16) * 64 + ck];
        }
#pragma unroll
        for (int i = 0; i < 4; i++)
#pragma unroll
          for (int j = 0; j < 4; j++)
            acc[i][j] = __builtin_amdgcn_mfma_f32_16x16x32_bf16(wf[j], af[i], acc[i][j], 0, 0, 0);
      }
    }
    // epilogue (transposed frag): row=quad*4+r -> feature, col=l16 -> token
    const float sc = (which == 0) ? QSCALE : 1.f;
    unsigned short* base = (which == 0) ? qb : kb;
#pragma unroll
    for (int i = 0; i < 4; i++) {
      const int tok = m0 + wr + i * 16 + l16;
      const int b = tok >> 11, n = tok & 2047;
#pragma unroll
      for (int j = 0; j < 4; j++) {
        const int col0 = n0 + wc + j * 16 + quad * 4;
        const int h = (col0 >> 6) & 15, d = col0 & 63;
        ushort4 o4;
        o4.x = f2bf(acc[i][j][0] * sc); o4.y = f2bf(acc[i][j][1] * sc);
        o4.z = f2bf(acc[i][j][2] * sc); o4.w = f2bf(acc[i][j][3] * sc);
        *(ushort4*)&base[((size_t)(b * 16 + h) * SEQ + n) * 64 + d] = o4;
      }
    }
  } else {
    for (int kt = 0; kt < K; kt += 64) {
      __syncthreads();
#pragma unroll
      for (int i = 0; i < 4; i++) {
        gload_lds16((const void*)(Ag + (size_t)(i * 32) * K + kt), (void*)&Al[(i * 32 + wave * 8) * 64]);
        gload_lds16((const void*)(Wg + (size_t)(i * 32) * K + kt), (void*)&Wl[(i * 32 + wave * 8) * 64]);
      }
      __syncthreads();
#pragma unroll
      for (int kk = 0; kk < 2; kk++) {
        bf16x8 af[4], wf[4];
#pragma unroll
        for (int i = 0; i < 4; i++) {
          const int ck = (((kk << 2) | quad) ^ sA) << 3;
          af[i] = *(const bf16x8*)&Al[(wr + i * 16 + l16) * 64 + ck];
          wf[i] = *(const bf16x8*)&Wl[(wc + i * 16 + l16) * 64 + ck];
        }
#pragma unroll
        for (int i = 0; i < 4; i++)
#pragma unroll
          for (int j = 0; j < 4; j++)
            acc[i][j] = __builtin_amdgcn_mfma_f32_16x16x32_bf16(af[i], wf[j], acc[i][j], 0, 0, 0);
      }
    }
    // epilogue (normal frag): 4 consecutive tokens per lane -> V^T fp16 ushort4
#pragma unroll
    for (int i = 0; i < 4; i++) {
      const int row = m0 + wr + i * 16 + quad * 4;
      const int b = row >> 11, n = row & 2047;
#pragma unroll
      for (int j = 0; j < 4; j++) {
        const int col = n0 + wc + j * 16 + l16;
        const int h = (col >> 6) & 15, d = col & 63;
        ushort4 o4;
        o4.x = f2h(acc[i][j][0]); o4.y = f2h(acc[i][j][1]);
        o4.z = f2h(acc[i][j][2]); o4.w = f2h(acc[i][j][3]);
        *(ushort4*)&vtb[((size_t)(b * 16 + h) * 64 + d) * SEQ + n] = o4;
      }
    }
  }
}

// ---- flash attention (R7 version, unchanged): R10 staging + tightened T5.
// LDS staging with 8-wave K/V sharing, 3 rotating buffers, prefetch
// distance 2, per-iter "s_waitcnt vmcnt(2) lgkmcnt(0); s_barrier" (2 newest
// gloads stay in flight across the barrier; waitcnt-then-barrier order
// REQUIRED for cooperative staging visibility). prio 1 only around MFMA
// clusters; exp/pkrtz chain at prio 0. Tail drains vmcnt(0). 48KB, 2 blk/CU.
__global__ __launch_bounds__(512, 4) void attn_kernel(
    const unsigned short* __restrict__ qb,   // [bh][n][d] bf16, pre-scaled by QSCALE
    const unsigned short* __restrict__ kb,   // [bh][n][d] bf16
    const unsigned short* __restrict__ vtb,  // [bh][d][n] fp16
    unsigned short* __restrict__ out) {      // [8192][1024] bf16
  __shared__ unsigned short Kl[3][64 * 64];  // [key][d], chunk c at c^sK(row)
  __shared__ unsigned short Vl[3][64 * 64];  // [d][key] fp16 bits, chunk c at c^(row&7)

  const int tid  = threadIdx.x;
  const int wave = tid >> 6, lane = tid & 63;
  const int quad = lane >> 4, l16 = lane & 15;
  const int bh    = blockIdx.x;           // 0..63  (XCD affinity)
  const int qtile = blockIdx.y;           // 0..7
  const size_t qkbase = (size_t)bh * SEQ * 64;
  const int q0 = qtile * 256 + wave * 32;

  // Q B-frags: Q[n=l16][k=kk*32+quad*8+j]  (kk = d-half here)
  bf16x8 qf[2][2];
#pragma unroll
  for (int mi = 0; mi < 2; mi++)
#pragma unroll
    for (int kk = 0; kk < 2; kk++)
      qf[mi][kk] = *(const bf16x8*)&qb[qkbase + (size_t)(q0 + mi * 16 + l16) * 64 + kk * 32 + quad * 8];

  f32x4 o[2][4];
#pragma unroll
  for (int mi = 0; mi < 2; mi++)
#pragma unroll
    for (int nt = 0; nt < 4; nt++) o[mi][nt] = (f32x4)0.f;
  f32x4 lacc[2];
#pragma unroll
  for (int mi = 0; mi < 2; mi++) lacc[mi] = (f32x4)0.f;

  union { f16x8 v; unsigned int d[4]; } ones8;
#pragma unroll
  for (int j = 0; j < 4; j++) ones8.d[j] = 0x3C003C00u;  // fp16 1.0 x8

  const unsigned short* Kg = kb + qkbase;
  const unsigned short* Vg = vtb + (size_t)bh * 64 * SEQ;
  const int srow = tid >> 3;   // 0..63 (512 threads cover 64 rows)
  const int schk = tid & 7;
  const int swK = (srow & 3) | (((srow >> 3) & 1) << 2);
  const int swV = srow & 7;

  auto stage = [&](int kt, int b) {
    gload_lds16((const void*)(Kg + (size_t)(kt + srow) * 64 + (schk ^ swK) * 8),
                (void*)&Kl[b][wave * 512]);
    gload_lds16((const void*)(Vg + (size_t)srow * SEQ + kt + (schk ^ swV) * 8),
                (void*)&Vl[b][wave * 512]);
  };

  stage(0, 0);    // 2 loads/thread
  stage(64, 1);   // 2 loads/thread

  const int rbase = ((l16 >> 2) << 3) + (l16 & 3);               // 8a + b
  const int sR = (l16 & 3) | (((l16 >> 2) & 1) << 2);            // K read swizzle

  int b0 = 0, b1 = 1, b2 = 2;
  for (int t = 0; t < 32; ++t) {
    // tile t landed; stage(t+1)'s 2 loads stay in flight across the barrier
    if (t < 31) asm volatile("s_waitcnt vmcnt(2) lgkmcnt(0)" ::: "memory");
    else        asm volatile("s_waitcnt vmcnt(0) lgkmcnt(0)" ::: "memory");
    __builtin_amdgcn_s_barrier();
    if (t + 2 < 32) stage((t + 2) * 64, b2);  // b2 = buffer read at iter t-1

    const unsigned short* Kc = &Kl[b0][0];
    const unsigned short* Vc = &Vl[b0][0];

#pragma unroll
    for (int kk = 0; kk < 2; kk++) {
      // K A-frags, permuted rows: T gives phys keys kk*32 + 8*(l16>>2) + (l16&3) + 4T
      bf16x8 kf[2][2];
#pragma unroll
      for (int T = 0; T < 2; T++) {
        const int R = kk * 32 + rbase + 4 * T;
        kf[T][0] = *(const bf16x8*)&Kc[R * 64 + ((quad ^ sR) << 3)];
        kf[T][1] = *(const bf16x8*)&Kc[R * 64 + (((4 + quad) ^ sR) << 3)];
      }
      // V B-frags: B[n=d=nt*16+l16][k=key=kk*32+quad*8+j]
      f16x8 vf[4];
#pragma unroll
      for (int nt = 0; nt < 4; nt++) {
        const int vr = nt * 16 + l16;
        vf[nt] = *(const f16x8*)&Vc[vr * 64 + (((kk * 4 + quad) ^ (vr & 7)) << 3)];
      }
#pragma unroll
      for (int mi = 0; mi < 2; mi++) {
        // S^T tiles: C[m -> phys key kk*32+8*quad+r(+4T)][n=q=l16]
        f32x4 s0 = (f32x4)0.f, s1 = (f32x4)0.f;
        __builtin_amdgcn_s_setprio(1);
        s0 = MFMA_BF16_K32(kf[0][0], qf[mi][0], s0);
        s0 = MFMA_BF16_K32(kf[0][1], qf[mi][1], s0);
        s1 = MFMA_BF16_K32(kf[1][0], qf[mi][0], s1);
        s1 = MFMA_BF16_K32(kf[1][1], qf[mi][1], s1);
        __builtin_amdgcn_s_setprio(0);
        // P A-frag (16x16x32 f16): exp chain at prio 0 (don't starve MFMA waves)
        union { f16x8 v; unsigned int d[4]; } pu;
        pu.d[0] = pkrtz_bits(EXP2F(s0[0]), EXP2F(s0[1]));
        pu.d[1] = pkrtz_bits(EXP2F(s0[2]), EXP2F(s0[3]));
        pu.d[2] = pkrtz_bits(EXP2F(s1[0]), EXP2F(s1[1]));
        pu.d[3] = pkrtz_bits(EXP2F(s1[2]), EXP2F(s1[3]));
        __builtin_amdgcn_s_setprio(1);
        lacc[mi] = MFMA_F16_K32(pu.v, ones8.v, lacc[mi]);
#pragma unroll
        for (int nt = 0; nt < 4; nt++)
          o[mi][nt] = MFMA_F16_K32(pu.v, vf[nt], o[mi][nt]);
        __builtin_amdgcn_s_setprio(0);
      }
    }
    const int tmp = b0; b0 = b1; b1 = b2; b2 = tmp;
  }

  const int h = bh & 15, b = bh >> 4;
#pragma unroll
  for (int mi = 0; mi < 2; mi++) {
    float inv[4];
#pragma unroll
    for (int r = 0; r < 4; r++) inv[r] = 1.f / lacc[mi][r];
#pragma unroll
    for (int nt = 0; nt < 4; nt++)
#pragma unroll
      for (int r = 0; r < 4; r++)
        out[((size_t)(b * SEQ + q0 + mi * 16 + quad * 4 + r)) * DIM + h * 64 + nt * 16 + l16] =
            f2bf(o[mi][nt][r] * inv[r]);
  }
}

// ---- proj GEMM (BK 32->64, same transformation as gemm_qkv) ----
__global__ __launch_bounds__(256) void gemm_proj(
    const unsigned short* __restrict__ A,
    const unsigned short* __restrict__ W,
    float* __restrict__ out,
    const float* __restrict__ bias) {
  const int N = DIM, K = DIM;
  __shared__ unsigned short Al[128 * 64];
  __shared__ unsigned short Wl[128 * 64];
  const int tid  = threadIdx.x;
  const int wave = tid >> 6, lane = tid & 63;
  const int quad = lane >> 4, l16 = lane & 15;
  const int m0 = blockIdx.y * 128, n0 = blockIdx.x * 128;
  const int wr = (wave >> 1) * 64, wc = (wave & 1) * 64;

  f32x4 acc[4][4];
#pragma unroll
  for (int i = 0; i < 4; i++)
#pragma unroll
    for (int j = 0; j < 4; j++) acc[i][j] = (f32x4)0.f;

  const int srow = wave * 8 + (lane >> 3);
  const int schk = (lane & 7) ^ ((lane >> 3) & 7);
  const unsigned short* Ag = A + (size_t)(m0 + srow) * K + (schk << 3);
  const unsigned short* Wg = W + (size_t)(n0 + srow) * K + (schk << 3);
  const int sA = l16 & 7;

  for (int kt = 0; kt < K; kt += 64) {
    __syncthreads();
#pragma unroll
    for (int i = 0; i < 4; i++) {
      gload_lds16((const void*)(Ag + (size_t)(i * 32) * K + kt), (void*)&Al[(i * 32 + wave * 8) * 64]);
      gload_lds16((const void*)(Wg + (size_t)(i * 32) * K + kt), (void*)&Wl[(i * 32 + wave * 8) * 64]);
    }
    __syncthreads();
#pragma unroll
    for (int kk = 0; kk < 2; kk++) {
      bf16x8 af[4], wf[4];
#pragma unroll
      for (int i = 0; i < 4; i++) {
        const int ck = (((kk << 2) | quad) ^ sA) << 3;
        af[i] = *(const bf16x8*)&Al[(wr + i * 16 + l16) * 64 + ck];
        wf[i] = *(const bf16x8*)&Wl[(wc + i * 16 + l16) * 64 + ck];
      }
#pragma unroll
      for (int i = 0; i < 4; i++)
#pragma unroll
        for (int j = 0; j < 4; j++)
          acc[i][j] = __builtin_amdgcn_mfma_f32_16x16x32_bf16(af[i], wf[j], acc[i][j], 0, 0, 0);
    }
  }

#pragma unroll
  for (int i = 0; i < 4; i++) {
    const int row = m0 + wr + i * 16 + quad * 4;
#pragma unroll
    for (int j = 0; j < 4; j++) {
      const int col = n0 + wc + j * 16 + l16;
      const float bv = bias[col];
#pragma unroll
      for (int r = 0; r < 4; r++)
        out[(size_t)(row + r) * N + col] = acc[i][j][r] + bv;
    }
  }
}

extern "C" void kernel_launch(void* const* d_in, const int* in_sizes, int n_in,
                              void* d_out, int out_size, void* d_ws, size_t ws_size,
                              hipStream_t stream) {
  const float* x      = (const float*)d_in[0];
  const float* w_qkv  = (const float*)d_in[1];
  const float* w_proj = (const float*)d_in[2];
  const float* b_proj = (const float*)d_in[3];
  float* outp = (float*)d_out;

  char* ws = (char*)d_ws;
  unsigned short* xb     = (unsigned short*)(ws);                        // 16 MB
  unsigned short* wqkvb  = (unsigned short*)(ws + (16u << 20));          // 6 MB
  unsigned short* wprojb = (unsigned short*)(ws + (22u << 20));          // 2 MB
  unsigned short* qb     = (unsigned short*)(ws + (24u << 20));          // 16 MB
  unsigned short* kb     = (unsigned short*)(ws + (40u << 20));          // 16 MB
  unsigned short* vtb    = (unsigned short*)(ws + (56u << 20));          // 16 MB (fp16)
  unsigned short* aout   = (unsigned short*)(ws + (72u << 20));          // 16 MB

  const int total4 = (ROWS * DIM + 3 * DIM * DIM + DIM * DIM) / 4;  // 3,145,728
  cast_all<<<total4 / 256, 256, 0, stream>>>(x, w_qkv, w_proj, xb, wqkvb, wprojb);

  gemm_qkv<<<dim3(24, 64), 256, 0, stream>>>(xb, wqkvb, qb, kb, vtb);
  attn_kernel<<<dim3(64, 8), 512, 0, stream>>>(qb, kb, vtb, aout);
  gemm_proj<<<dim3(8, 64), 256, 0, stream>>>(aout, wprojb, outp, b_proj);
}